// Round 8
// baseline (215.268 us; speedup 1.0000x reference)
//
#include <hip/hip_runtime.h>
#include <math.h>

#define D_MODEL 512
#define STATE_DIM 16
#define MASK_BUCKETS 2048
#define PPB 256              // points per block; divides N=65536 -> one batch per block
#define N_STATE_BLOCKS 16    // 8 batches x 2 halves of D

typedef float v4f __attribute__((ext_vector_type(4)));
typedef int   v4i __attribute__((ext_vector_type(4)));

__device__ __forceinline__ v4f f4_load(const float* p) { return *(const v4f*)p; }
__device__ __forceinline__ v4f f4_fma(float s, v4f a, v4f b) {
    return (v4f){fmaf(s, a.x, b.x), fmaf(s, a.y, b.y), fmaf(s, a.z, b.z), fmaf(s, a.w, b.w)};
}

// Blocks [0,16): state token (overlapped). Blocks [16,...): 256 points each.
// R7 A/B vs R6: inner loop unrolled 2 -> 4 points per thread-iter so 4
// gathers + 4 NT stores are outstanding; tests whether vmcnt/store-queue
// depth (not the NT drain rate) is the residual bottleneck.
__global__ __launch_bounds__(256) void fused_proj_kernel(
    const float* __restrict__ xyz,
    const float* __restrict__ state,
    const float* __restrict__ rgb,
    const int*   __restrict__ mask_id,
    const float* __restrict__ Wxyz,
    const float* __restrict__ Wrgb,
    const float* __restrict__ rgb_alpha,
    const float* __restrict__ Wg,
    const float* __restrict__ gripper_alpha,
    const float* __restrict__ Ws1,
    const float* __restrict__ bs1,
    const float* __restrict__ Ws2,
    const float* __restrict__ bs2,
    const float* __restrict__ mask_embed,
    float* __restrict__ out,
    long long total_points,
    int n_points)  // N per batch
{
    const int tid = threadIdx.x;

    if (blockIdx.x < N_STATE_BLOCKS) {
        // ---------------- state token path ----------------
        __shared__ float u[D_MODEL];
        const int b    = blockIdx.x >> 1;
        const int half = blockIdx.x & 1;

        #pragma unroll
        for (int r = 0; r < 2; ++r) {
            const int j = tid + r * 256;
            float acc = bs1[j];
            #pragma unroll
            for (int k = 0; k < STATE_DIM; ++k)
                acc = fmaf(state[b * STATE_DIM + k], Ws1[k * D_MODEL + j], acc);
            u[j] = acc / (1.0f + expf(-acc));   // silu
        }
        __syncthreads();

        const int c = half * 256 + tid;
        float acc2 = bs2[c];
        #pragma unroll 8
        for (int k = 0; k < D_MODEL; ++k)
            acc2 = fmaf(u[k], Ws2[k * D_MODEL + c], acc2);

        out[(size_t)total_points * D_MODEL + (size_t)b * D_MODEL + c] = acc2;
        return;
    }

    // ---------------- point path ----------------
    __shared__ float sXYZ[3 * PPB];   // raw staged xyz (3 KB)
    __shared__ float sRGB[3 * PPB];   // raw staged rgb (3 KB)
    __shared__ int   sM[PPB];         // raw staged mask ids (1 KB)
    __shared__ v4f   sA[PPB];         // packed {x, y, z, dist} (4 KB)
    __shared__ v4f   sB[PPB];         // packed {r0, r1, r2, bitcast(m)} (4 KB)

    const int d   = (tid & 127) << 2;   // float4 column slice of D=512
    const int sub = tid >> 7;           // point parity within an iter-group

    const float ra = rgb_alpha[0];
    const float ga = gripper_alpha[0];

    const long long p0 = (long long)(blockIdx.x - N_STATE_BLOCKS) * PPB;
    const int b = (int)(p0 / n_points);

    const float gx = state[b * STATE_DIM + 0];
    const float gy = state[b * STATE_DIM + 1];
    const float gz = state[b * STATE_DIM + 2];

    // --- phase A: vectorized raw staging (NT: stream-once inputs) ---
    if (tid < 192) {
        ((v4f*)sXYZ)[tid] = __builtin_nontemporal_load((const v4f*)(xyz + p0 * 3) + tid);
        ((v4f*)sRGB)[tid] = __builtin_nontemporal_load((const v4f*)(rgb + p0 * 3) + tid);
    } else {
        const int t = tid - 192;
        ((v4i*)sM)[t] = __builtin_nontemporal_load((const v4i*)(mask_id + p0) + t);
    }

    // fold weights into registers while staging loads are in flight
    v4f G0 = f4_load(&Wg[0 * D_MODEL + d]) * ga;
    v4f G1 = f4_load(&Wg[1 * D_MODEL + d]) * ga;
    v4f G2 = f4_load(&Wg[2 * D_MODEL + d]) * ga;
    v4f G3 = f4_load(&Wg[3 * D_MODEL + d]) * ga;
    v4f Cb = -(G0 * gx + G1 * gy + G2 * gz);       // -ga*(gxyz . Wg[0:3])
    v4f A0 = f4_load(&Wxyz[0 * D_MODEL + d]) + G0;
    v4f A1 = f4_load(&Wxyz[1 * D_MODEL + d]) + G1;
    v4f A2 = f4_load(&Wxyz[2 * D_MODEL + d]) + G2;
    v4f R0 = f4_load(&Wrgb[0 * D_MODEL + d]) * ra;
    v4f R1 = f4_load(&Wrgb[1 * D_MODEL + d]) * ra;
    v4f R2 = f4_load(&Wrgb[2 * D_MODEL + d]) * ra;

    __syncthreads();

    // --- phase B: pack per-point scalars, dist computed ONCE per point ---
    {
        const float x = sXYZ[3 * tid + 0];
        const float y = sXYZ[3 * tid + 1];
        const float z = sXYZ[3 * tid + 2];
        const float rx = x - gx, ry = y - gy, rz = z - gz;
        const float dist = sqrtf(rx * rx + ry * ry + rz * rz);
        sA[tid] = (v4f){x, y, z, dist};
        sB[tid] = (v4f){sRGB[3 * tid + 0], sRGB[3 * tid + 1], sRGB[3 * tid + 2],
                        __int_as_float(sM[tid] & (MASK_BUCKETS - 1))};
    }
    __syncthreads();

    // --- phase C: inner loop, 4 points in flight per thread ---
    for (int i = 0; i < PPB / 8; ++i) {
        const int q0 = (i << 3) + sub;
        const int q1 = q0 + 2;
        const int q2 = q0 + 4;
        const int q3 = q0 + 6;

        // broadcast LDS reads (uniform addr per wave)
        const v4f a0 = sA[q0], b0 = sB[q0];
        const v4f a1 = sA[q1], b1 = sB[q1];
        const v4f a2 = sA[q2], b2 = sB[q2];
        const v4f a3 = sA[q3], b3 = sB[q3];

        // 4 gathers in flight (plain loads: table stays L2-resident)
        const v4f me0 = f4_load(&mask_embed[(size_t)__float_as_int(b0.w) * D_MODEL + d]);
        const v4f me1 = f4_load(&mask_embed[(size_t)__float_as_int(b1.w) * D_MODEL + d]);
        const v4f me2 = f4_load(&mask_embed[(size_t)__float_as_int(b2.w) * D_MODEL + d]);
        const v4f me3 = f4_load(&mask_embed[(size_t)__float_as_int(b3.w) * D_MODEL + d]);

        v4f o0 = Cb + me0;
        o0 = f4_fma(a0.x, A0, o0); o0 = f4_fma(a0.y, A1, o0); o0 = f4_fma(a0.z, A2, o0);
        o0 = f4_fma(b0.x, R0, o0); o0 = f4_fma(b0.y, R1, o0); o0 = f4_fma(b0.z, R2, o0);
        o0 = f4_fma(a0.w, G3, o0);

        v4f o1 = Cb + me1;
        o1 = f4_fma(a1.x, A0, o1); o1 = f4_fma(a1.y, A1, o1); o1 = f4_fma(a1.z, A2, o1);
        o1 = f4_fma(b1.x, R0, o1); o1 = f4_fma(b1.y, R1, o1); o1 = f4_fma(b1.z, R2, o1);
        o1 = f4_fma(a1.w, G3, o1);

        v4f o2 = Cb + me2;
        o2 = f4_fma(a2.x, A0, o2); o2 = f4_fma(a2.y, A1, o2); o2 = f4_fma(a2.z, A2, o2);
        o2 = f4_fma(b2.x, R0, o2); o2 = f4_fma(b2.y, R1, o2); o2 = f4_fma(b2.z, R2, o2);
        o2 = f4_fma(a2.w, G3, o2);

        v4f o3 = Cb + me3;
        o3 = f4_fma(a3.x, A0, o3); o3 = f4_fma(a3.y, A1, o3); o3 = f4_fma(a3.z, A2, o3);
        o3 = f4_fma(b3.x, R0, o3); o3 = f4_fma(b3.y, R1, o3); o3 = f4_fma(b3.z, R2, o3);
        o3 = f4_fma(a3.w, G3, o3);

        // 4 NT stores outstanding (NT mandatory: R5 plain stores -> 356us)
        __builtin_nontemporal_store(o0, (v4f*)&out[(size_t)(p0 + q0) * D_MODEL + d]);
        __builtin_nontemporal_store(o1, (v4f*)&out[(size_t)(p0 + q1) * D_MODEL + d]);
        __builtin_nontemporal_store(o2, (v4f*)&out[(size_t)(p0 + q2) * D_MODEL + d]);
        __builtin_nontemporal_store(o3, (v4f*)&out[(size_t)(p0 + q3) * D_MODEL + d]);
    }
}

extern "C" void kernel_launch(void* const* d_in, const int* in_sizes, int n_in,
                              void* d_out, int out_size, void* d_ws, size_t ws_size,
                              hipStream_t stream) {
    const float* xyz           = (const float*)d_in[0];
    const float* state         = (const float*)d_in[1];
    const float* rgb           = (const float*)d_in[2];
    const int*   mask_id       = (const int*)  d_in[3];
    const float* Wxyz          = (const float*)d_in[4];
    const float* Wrgb          = (const float*)d_in[5];
    const float* rgb_alpha     = (const float*)d_in[6];
    const float* Wg            = (const float*)d_in[7];
    const float* gripper_alpha = (const float*)d_in[8];
    const float* Ws1           = (const float*)d_in[9];
    const float* bs1           = (const float*)d_in[10];
    const float* Ws2           = (const float*)d_in[11];
    const float* bs2           = (const float*)d_in[12];
    const float* mask_embed    = (const float*)d_in[13];
    float* out = (float*)d_out;

    const int B = in_sizes[1] / STATE_DIM;              // 8
    const long long total_points = in_sizes[3];         // B*N = 524288
    const int N = (int)(total_points / B);              // 65536

    const int grid = N_STATE_BLOCKS + (int)(total_points / PPB);  // 16 + 2048

    fused_proj_kernel<<<grid, 256, 0, stream>>>(
        xyz, state, rgb, mask_id, Wxyz, Wrgb, rgb_alpha, Wg, gripper_alpha,
        Ws1, bs1, Ws2, bs2, mask_embed, out, total_points, N);
}

// Round 9
// 214.678 us; speedup vs baseline: 1.0028x; 1.0028x over previous
//
#include <hip/hip_runtime.h>
#include <math.h>

#define D_MODEL 512
#define STATE_DIM 16
#define MASK_BUCKETS 2048
#define PPB 256              // points per block; divides N=65536 -> one batch per block
#define N_STATE_BLOCKS 16    // 8 batches x 2 halves of D

typedef float v4f __attribute__((ext_vector_type(4)));
typedef int   v4i __attribute__((ext_vector_type(4)));

__device__ __forceinline__ v4f f4_load(const float* p) { return *(const v4f*)p; }
__device__ __forceinline__ v4f f4_fma(float s, v4f a, v4f b) {
    return (v4f){fmaf(s, a.x, b.x), fmaf(s, a.y, b.y), fmaf(s, a.z, b.z), fmaf(s, a.w, b.w)};
}

// R8 A/B vs R7: output stores via inline-asm global_store_dwordx4 with the
// full cache-policy bypass "sc0 sc1 nt" (system-scope, no-allocate,
// non-temporal) instead of __builtin_nontemporal_store's bare "nt".
// Tests whether the bare-nt path's ~5.2 TB/s drain (vs 6.6 TB/s plain-store
// fill) is an L2-arbitration artifact that full bypass avoids.
__device__ __forceinline__ void store_bypass(v4f v, float* p) {
    asm volatile("global_store_dwordx4 %0, %1, off sc0 sc1 nt"
                 :: "v"(p), "v"(v) : "memory");
}

__global__ __launch_bounds__(256) void fused_proj_kernel(
    const float* __restrict__ xyz,
    const float* __restrict__ state,
    const float* __restrict__ rgb,
    const int*   __restrict__ mask_id,
    const float* __restrict__ Wxyz,
    const float* __restrict__ Wrgb,
    const float* __restrict__ rgb_alpha,
    const float* __restrict__ Wg,
    const float* __restrict__ gripper_alpha,
    const float* __restrict__ Ws1,
    const float* __restrict__ bs1,
    const float* __restrict__ Ws2,
    const float* __restrict__ bs2,
    const float* __restrict__ mask_embed,
    float* __restrict__ out,
    long long total_points,
    int n_points)  // N per batch
{
    const int tid = threadIdx.x;

    if (blockIdx.x < N_STATE_BLOCKS) {
        // ---------------- state token path ----------------
        __shared__ float u[D_MODEL];
        const int b    = blockIdx.x >> 1;
        const int half = blockIdx.x & 1;

        #pragma unroll
        for (int r = 0; r < 2; ++r) {
            const int j = tid + r * 256;
            float acc = bs1[j];
            #pragma unroll
            for (int k = 0; k < STATE_DIM; ++k)
                acc = fmaf(state[b * STATE_DIM + k], Ws1[k * D_MODEL + j], acc);
            u[j] = acc / (1.0f + expf(-acc));   // silu
        }
        __syncthreads();

        const int c = half * 256 + tid;
        float acc2 = bs2[c];
        #pragma unroll 8
        for (int k = 0; k < D_MODEL; ++k)
            acc2 = fmaf(u[k], Ws2[k * D_MODEL + c], acc2);

        out[(size_t)total_points * D_MODEL + (size_t)b * D_MODEL + c] = acc2;
        return;
    }

    // ---------------- point path ----------------
    __shared__ float sXYZ[3 * PPB];   // raw staged xyz (3 KB)
    __shared__ float sRGB[3 * PPB];   // raw staged rgb (3 KB)
    __shared__ int   sM[PPB];         // raw staged mask ids (1 KB)
    __shared__ v4f   sA[PPB];         // packed {x, y, z, dist} (4 KB)
    __shared__ v4f   sB[PPB];         // packed {r0, r1, r2, bitcast(m)} (4 KB)

    const int d   = (tid & 127) << 2;   // float4 column slice of D=512
    const int sub = tid >> 7;           // point parity within an iter-group

    const float ra = rgb_alpha[0];
    const float ga = gripper_alpha[0];

    const long long p0 = (long long)(blockIdx.x - N_STATE_BLOCKS) * PPB;
    const int b = (int)(p0 / n_points);

    const float gx = state[b * STATE_DIM + 0];
    const float gy = state[b * STATE_DIM + 1];
    const float gz = state[b * STATE_DIM + 2];

    // --- phase A: vectorized raw staging (NT loads: stream-once inputs) ---
    if (tid < 192) {
        ((v4f*)sXYZ)[tid] = __builtin_nontemporal_load((const v4f*)(xyz + p0 * 3) + tid);
        ((v4f*)sRGB)[tid] = __builtin_nontemporal_load((const v4f*)(rgb + p0 * 3) + tid);
    } else {
        const int t = tid - 192;
        ((v4i*)sM)[t] = __builtin_nontemporal_load((const v4i*)(mask_id + p0) + t);
    }

    // fold weights into registers while staging loads are in flight
    v4f G0 = f4_load(&Wg[0 * D_MODEL + d]) * ga;
    v4f G1 = f4_load(&Wg[1 * D_MODEL + d]) * ga;
    v4f G2 = f4_load(&Wg[2 * D_MODEL + d]) * ga;
    v4f G3 = f4_load(&Wg[3 * D_MODEL + d]) * ga;
    v4f Cb = -(G0 * gx + G1 * gy + G2 * gz);       // -ga*(gxyz . Wg[0:3])
    v4f A0 = f4_load(&Wxyz[0 * D_MODEL + d]) + G0;
    v4f A1 = f4_load(&Wxyz[1 * D_MODEL + d]) + G1;
    v4f A2 = f4_load(&Wxyz[2 * D_MODEL + d]) + G2;
    v4f R0 = f4_load(&Wrgb[0 * D_MODEL + d]) * ra;
    v4f R1 = f4_load(&Wrgb[1 * D_MODEL + d]) * ra;
    v4f R2 = f4_load(&Wrgb[2 * D_MODEL + d]) * ra;

    __syncthreads();

    // --- phase B: pack per-point scalars, dist computed ONCE per point ---
    {
        const float x = sXYZ[3 * tid + 0];
        const float y = sXYZ[3 * tid + 1];
        const float z = sXYZ[3 * tid + 2];
        const float rx = x - gx, ry = y - gy, rz = z - gz;
        const float dist = sqrtf(rx * rx + ry * ry + rz * rz);
        sA[tid] = (v4f){x, y, z, dist};
        sB[tid] = (v4f){sRGB[3 * tid + 0], sRGB[3 * tid + 1], sRGB[3 * tid + 2],
                        __int_as_float(sM[tid] & (MASK_BUCKETS - 1))};
    }
    __syncthreads();

    // --- phase C: inner loop, 4 points in flight per thread ---
    for (int i = 0; i < PPB / 8; ++i) {
        const int q0 = (i << 3) + sub;
        const int q1 = q0 + 2;
        const int q2 = q0 + 4;
        const int q3 = q0 + 6;

        // broadcast LDS reads (uniform addr per wave)
        const v4f a0 = sA[q0], b0 = sB[q0];
        const v4f a1 = sA[q1], b1 = sB[q1];
        const v4f a2 = sA[q2], b2 = sB[q2];
        const v4f a3 = sA[q3], b3 = sB[q3];

        // 4 gathers in flight (plain loads: table stays L2-resident)
        const v4f me0 = f4_load(&mask_embed[(size_t)__float_as_int(b0.w) * D_MODEL + d]);
        const v4f me1 = f4_load(&mask_embed[(size_t)__float_as_int(b1.w) * D_MODEL + d]);
        const v4f me2 = f4_load(&mask_embed[(size_t)__float_as_int(b2.w) * D_MODEL + d]);
        const v4f me3 = f4_load(&mask_embed[(size_t)__float_as_int(b3.w) * D_MODEL + d]);

        v4f o0 = Cb + me0;
        o0 = f4_fma(a0.x, A0, o0); o0 = f4_fma(a0.y, A1, o0); o0 = f4_fma(a0.z, A2, o0);
        o0 = f4_fma(b0.x, R0, o0); o0 = f4_fma(b0.y, R1, o0); o0 = f4_fma(b0.z, R2, o0);
        o0 = f4_fma(a0.w, G3, o0);

        v4f o1 = Cb + me1;
        o1 = f4_fma(a1.x, A0, o1); o1 = f4_fma(a1.y, A1, o1); o1 = f4_fma(a1.z, A2, o1);
        o1 = f4_fma(b1.x, R0, o1); o1 = f4_fma(b1.y, R1, o1); o1 = f4_fma(b1.z, R2, o1);
        o1 = f4_fma(a1.w, G3, o1);

        v4f o2 = Cb + me2;
        o2 = f4_fma(a2.x, A0, o2); o2 = f4_fma(a2.y, A1, o2); o2 = f4_fma(a2.z, A2, o2);
        o2 = f4_fma(b2.x, R0, o2); o2 = f4_fma(b2.y, R1, o2); o2 = f4_fma(b2.z, R2, o2);
        o2 = f4_fma(a2.w, G3, o2);

        v4f o3 = Cb + me3;
        o3 = f4_fma(a3.x, A0, o3); o3 = f4_fma(a3.y, A1, o3); o3 = f4_fma(a3.z, A2, o3);
        o3 = f4_fma(b3.x, R0, o3); o3 = f4_fma(b3.y, R1, o3); o3 = f4_fma(b3.z, R2, o3);
        o3 = f4_fma(a3.w, G3, o3);

        // A/B variable: sc0 sc1 nt bypass stores (vs R7's bare nt)
        store_bypass(o0, &out[(size_t)(p0 + q0) * D_MODEL + d]);
        store_bypass(o1, &out[(size_t)(p0 + q1) * D_MODEL + d]);
        store_bypass(o2, &out[(size_t)(p0 + q2) * D_MODEL + d]);
        store_bypass(o3, &out[(size_t)(p0 + q3) * D_MODEL + d]);
    }
}

extern "C" void kernel_launch(void* const* d_in, const int* in_sizes, int n_in,
                              void* d_out, int out_size, void* d_ws, size_t ws_size,
                              hipStream_t stream) {
    const float* xyz           = (const float*)d_in[0];
    const float* state         = (const float*)d_in[1];
    const float* rgb           = (const float*)d_in[2];
    const int*   mask_id       = (const int*)  d_in[3];
    const float* Wxyz          = (const float*)d_in[4];
    const float* Wrgb          = (const float*)d_in[5];
    const float* rgb_alpha     = (const float*)d_in[6];
    const float* Wg            = (const float*)d_in[7];
    const float* gripper_alpha = (const float*)d_in[8];
    const float* Ws1           = (const float*)d_in[9];
    const float* bs1           = (const float*)d_in[10];
    const float* Ws2           = (const float*)d_in[11];
    const float* bs2           = (const float*)d_in[12];
    const float* mask_embed    = (const float*)d_in[13];
    float* out = (float*)d_out;

    const int B = in_sizes[1] / STATE_DIM;              // 8
    const long long total_points = in_sizes[3];         // B*N = 524288
    const int N = (int)(total_points / B);              // 65536

    const int grid = N_STATE_BLOCKS + (int)(total_points / PPB);  // 16 + 2048

    fused_proj_kernel<<<grid, 256, 0, stream>>>(
        xyz, state, rgb, mask_id, Wxyz, Wrgb, rgb_alpha, Wg, gripper_alpha,
        Ws1, bs1, Ws2, bs2, mask_embed, out, total_points, N);
}